// Round 1
// baseline (43.199 us; speedup 1.0000x reference)
//
#include <hip/hip_runtime.h>
#include <math.h>

// Problem constants (fixed by reference setup_inputs)
#define B_N   16
#define W_IN  64
#define H_IN  64
#define C_IN  8
#define D_OUT 4
#define NXo   63
#define NYo   63
#define NLRN  6
#define TOT   (B_N * NXo * NYo * D_OUT)   // 254016 output elements

static __device__ __forceinline__ float2 cmul(float2 a, float2 b) {
    return make_float2(fmaf(a.x, b.x, -a.y * b.y), fmaf(a.x, b.y, a.y * b.x));
}
static __device__ __forceinline__ float2 cadd(float2 a, float2 b) {
    return make_float2(a.x + b.x, a.y + b.y);
}

// Apply CZ^e then CX^e on (control mask MC, target mask MT).
// gp: {ph.re, ph.im, cc.re, cc.im, ss.re, ss.im}
template <int MC, int MT>
static __device__ __forceinline__ void apply_czcx(float2* A, const float* gp) {
    const float2 ph = make_float2(gp[0], gp[1]);
    const float2 cc = make_float2(gp[2], gp[3]);
    const float2 ss = make_float2(gp[4], gp[5]);
#pragma unroll
    for (int idx = 0; idx < 16; ++idx) {
        if ((idx & MC) && (idx & MT)) A[idx] = cmul(A[idx], ph);  // CZPow
    }
#pragma unroll
    for (int idx = 0; idx < 16; ++idx) {
        if ((idx & MC) && !(idx & MT)) {   // CXPow on control=1 subspace
            float2 x = A[idx], y = A[idx | MT];
            A[idx]      = cadd(cmul(cc, x), cmul(ss, y));
            A[idx | MT] = cadd(cmul(ss, x), cmul(cc, y));
        }
    }
}

// 4-qubit sim: product-state init from (cq,sq), 3 CZ/CX gate pairs, <Z0>.
static __device__ __forceinline__ float simulate(const float* cq, const float* sq,
                                                 const float* gp) {
    // qubit q bit value in idx: mask(q) = 8 >> q  (cirq: qubit 0 leading)
    float2 t01[4] = {
        make_float2(cq[0] * cq[1], 0.f),
        make_float2(0.f, -cq[0] * sq[1]),
        make_float2(0.f, -sq[0] * cq[1]),
        make_float2(-sq[0] * sq[1], 0.f),
    };
    float2 t23[4] = {
        make_float2(cq[2] * cq[3], 0.f),
        make_float2(0.f, -cq[2] * sq[3]),
        make_float2(0.f, -sq[2] * cq[3]),
        make_float2(-sq[2] * sq[3], 0.f),
    };
    float2 A[16];
#pragma unroll
    for (int u = 0; u < 4; ++u)
#pragma unroll
        for (int v = 0; v < 4; ++v) A[u * 4 + v] = cmul(t01[u], t23[v]);

    apply_czcx<8, 4>(A, gp + 0);   // qubits (0,1): p[0], p[1]
    apply_czcx<2, 1>(A, gp + 6);   // qubits (2,3): p[2], p[3]
    apply_czcx<8, 2>(A, gp + 12);  // qubits (0,2): p[4], p[5]

    float p0 = 0.f, p1 = 0.f;
#pragma unroll
    for (int idx = 0; idx < 8; ++idx)  p0 = fmaf(A[idx].x, A[idx].x, fmaf(A[idx].y, A[idx].y, p0));
#pragma unroll
    for (int idx = 8; idx < 16; ++idx) p1 = fmaf(A[idx].x, A[idx].x, fmaf(A[idx].y, A[idx].y, p1));
    return p0 - p1;
}

__global__ __launch_bounds__(256) void qconv_kernel(const float* __restrict__ x,
                                                    const float* __restrict__ kern,
                                                    float* __restrict__ out) {
    constexpr float PI_F = 3.14159265358979323846f;
    // Per-(d,c,gate) precomputed complex gate entries: 4*8*3*6 = 576 floats
    __shared__ float tab[D_OUT * C_IN * 3 * 6];

    int t = threadIdx.x;
    if (t < D_OUT * C_IN * 3) {
        int g = t % 3;
        int dc = t / 3;                       // dc = d*C_IN + c, matches kernel layout
        float e_cz = kern[dc * NLRN + 2 * g];
        float e_cx = kern[dc * NLRN + 2 * g + 1];
        float sz, cz;
        sincosf(PI_F * e_cz, &sz, &cz);       // ph = e^{i*pi*e_cz}
        float h = 0.5f * PI_F * e_cx;
        float sh, ch;
        sincosf(h, &sh, &ch);
        float* o = tab + dc * 18 + g * 6;
        o[0] = cz;                            // ph.re
        o[1] = sz;                            // ph.im
        o[2] = ch * ch;                       // cc = e^{ih} cos h
        o[3] = sh * ch;
        o[4] = sh * sh;                       // ss = -i e^{ih} sin h
        o[5] = -sh * ch;
    }
    __syncthreads();

    int gid = blockIdx.x * blockDim.x + threadIdx.x;
    if (gid >= TOT) return;

    int d = gid & 3;
    int pos = gid >> 2;
    int j = pos % NYo;
    int tmp = pos / NYo;
    int i = tmp % NXo;
    int b = tmp / NXo;

    // x[b][w][h][c]: strides c:1, h:8, w:512, b:32768
    const float* xb = x + ((b * W_IN + i) * H_IN + j) * C_IN;
    const float* gpd = tab + d * C_IN * 18;

    float acc = 0.f;
#pragma unroll
    for (int c = 0; c < C_IN; ++c) {
        // patch pixels row-major (di,dj): (0,0) (0,1) (1,0) (1,1)
        float a0 = xb[c];
        float a1 = xb[c + C_IN];
        float a2 = xb[c + H_IN * C_IN];
        float a3 = xb[c + H_IN * C_IN + C_IN];
        float cq[4], sq[4];
        sincosf(0.5f * PI_F * a0, &sq[0], &cq[0]);
        sincosf(0.5f * PI_F * a1, &sq[1], &cq[1]);
        sincosf(0.5f * PI_F * a2, &sq[2], &cq[2]);
        sincosf(0.5f * PI_F * a3, &sq[3], &cq[3]);
        acc += simulate(cq, sq, gpd + c * 18);
    }

    float v = fminf(fmaxf(acc, -1.0f + 1e-5f), 1.0f - 1e-5f);
    out[gid] = acosf(v) * (1.0f / PI_F);
}

extern "C" void kernel_launch(void* const* d_in, const int* in_sizes, int n_in,
                              void* d_out, int out_size, void* d_ws, size_t ws_size,
                              hipStream_t stream) {
    const float* x = (const float*)d_in[0];      // [16,64,64,8] f32
    const float* kern = (const float*)d_in[1];   // [4,8,6] f32
    float* out = (float*)d_out;                  // [16,63,63,4] f32

    int blocks = (TOT + 255) / 256;
    qconv_kernel<<<blocks, 256, 0, stream>>>(x, kern, out);
}

// Round 2
// 9.660 us; speedup vs baseline: 4.4719x; 4.4719x over previous
//
#include <hip/hip_runtime.h>
#include <math.h>

// Problem constants (fixed by reference setup_inputs)
#define B_N   16
#define W_IN  64
#define H_IN  64
#define C_IN  8
#define D_OUT 4
#define NXo   63
#define NYo   63
#define NPOS  (B_N * NXo * NYo)   // 63504 output positions; out has ×4 d-broadcast

// Analytic collapse of the QCNN circuit:
// CZPow is diagonal; CXPow(e) is block-diagonal in its first (control) qubit.
// Qubit 0 (the measured one) is the preserved qubit of gate pairs (0,1) and
// (0,2), and pair (2,3) doesn't touch it. Hence P(q0) is invariant under the
// whole learned circuit and <Z0> = cos^2(pi*a0/2) - sin^2(pi*a0/2)
// = cos(pi * a0), with a0 = patch pixel (di=0,dj=0) = x[b,i,j,c].
// out[b,i,j,d] = arccos(clip(sum_c cos(pi*x[b,i,j,c]), -1+1e-5, 1-1e-5)) / pi
// for every d (kernel weights cancel in the forward pass).

__global__ __launch_bounds__(256) void qconv_kernel(const float* __restrict__ x,
                                                    float* __restrict__ out) {
    constexpr float PI_F = 3.14159265358979323846f;
    int gid = blockIdx.x * blockDim.x + threadIdx.x;
    if (gid >= NPOS) return;

    int j = gid % NYo;
    int t = gid / NYo;
    int i = t % NXo;
    int b = t / NXo;

    // x[b][i][j][0..7]: contiguous 8 floats, 32B-aligned
    const float4* p = (const float4*)(x + ((b * W_IN + i) * H_IN + j) * C_IN);
    float4 lo = p[0];
    float4 hi = p[1];

    float s = cosf(PI_F * lo.x) + cosf(PI_F * lo.y) +
              cosf(PI_F * lo.z) + cosf(PI_F * lo.w) +
              cosf(PI_F * hi.x) + cosf(PI_F * hi.y) +
              cosf(PI_F * hi.z) + cosf(PI_F * hi.w);

    float v = fminf(fmaxf(s, -1.0f + 1e-5f), 1.0f - 1e-5f);
    float r = acosf(v) * (1.0f / PI_F);

    // out[b][i][j][d] for d=0..3 — identical along d; 16B-aligned float4 store
    ((float4*)out)[gid] = make_float4(r, r, r, r);
}

extern "C" void kernel_launch(void* const* d_in, const int* in_sizes, int n_in,
                              void* d_out, int out_size, void* d_ws, size_t ws_size,
                              hipStream_t stream) {
    const float* x = (const float*)d_in[0];   // [16,64,64,8] f32
    float* out = (float*)d_out;               // [16,63,63,4] f32

    int blocks = (NPOS + 255) / 256;
    qconv_kernel<<<blocks, 256, 0, stream>>>(x, out);
}